// Round 9
// baseline (360.342 us; speedup 1.0000x reference)
//
#include <hip/hip_runtime.h>

#define AS1 __attribute__((address_space(1)))
#define AS3 __attribute__((address_space(3)))

typedef __attribute__((ext_vector_type(8))) _Float16 f16x8;
typedef __attribute__((ext_vector_type(4))) _Float16 f16x4;
typedef __attribute__((ext_vector_type(4))) float f32x4;

#define MFMA_K16(a, b, c) __builtin_amdgcn_mfma_f32_16x16x16f16(a, b, c, 0, 0, 0)

__device__ __forceinline__ unsigned short f2h(float f) {
    union { _Float16 h; unsigned short u; } v; v.h = (_Float16)f; return v.u;
}

__device__ __forceinline__ void gload16(const void* g, void* l) {
    __builtin_amdgcn_global_load_lds((const AS1 unsigned int*)g, (AS3 unsigned int*)l, 16, 0, 0);
}

#define GBAR() __builtin_amdgcn_s_barrier()
#define VM4()  asm volatile("s_waitcnt vmcnt(4)" ::: "memory")
#define VM0()  asm volatile("s_waitcnt vmcnt(0)" ::: "memory")

// ---------- f32 -> fp16 elementwise (x4 vectorized) ----------
__global__ __launch_bounds__(256) void k_cvt(const float* __restrict__ src,
                                             unsigned short* __restrict__ dst, int n4) {
    int i = blockIdx.x * 256 + threadIdx.x;
    if (i >= n4) return;
    float4 v = ((const float4*)src)[i];
    ushort4 o;
    o.x = f2h(v.x); o.y = f2h(v.y); o.z = f2h(v.z); o.w = f2h(v.w);
    ((ushort4*)dst)[i] = o;
}

// ---------- tiled transpose + convert: dst[c*ld_dst + r] = fp16(src[r*ld_src + c]) ----------
__global__ __launch_bounds__(256) void k_transpose_cvt(const float* __restrict__ src,
                                                       unsigned short* __restrict__ dst,
                                                       int ld_src, int ld_dst,
                                                       long zs_src, long zs_dst) {
    __shared__ float tile[32][33];
    long sb = (long)blockIdx.z * zs_src;
    long db = (long)blockIdx.z * zs_dst;
    int c0 = blockIdx.x * 32, r0 = blockIdx.y * 32;
    int tx = threadIdx.x, ty = threadIdx.y;
#pragma unroll
    for (int i = 0; i < 4; i++)
        tile[ty + i * 8][tx] = src[sb + (long)(r0 + ty + i * 8) * ld_src + c0 + tx];
    __syncthreads();
#pragma unroll
    for (int i = 0; i < 4; i++)
        dst[db + (long)(c0 + ty + i * 8) * ld_dst + r0 + tx] = f2h(tile[tx][ty + i * 8]);
}

// ======== 256x256 8-phase fp16 GEMM (T2+T3+T4+T5): C = A(MxK) * Bt(NxK)^T, f32 out ========
template<int BUF, int MIH>
__device__ __forceinline__ void rdA(const unsigned short* SA, int wm, int fr, int g,
                                    f16x8 (&af)[4][2]) {
#pragma unroll
    for (int m = 0; m < 4; m++)
#pragma unroll
        for (int kk = 0; kk < 2; kk++) {
            int pos = wm * 64 + m * 16 + fr;
            af[m][kk] = *(const f16x8*)(SA + BUF * 16384 + MIH * 8192 + pos * 64 +
                                        (((kk * 4 + g) ^ (fr & 7)) << 3));
        }
}

template<int BUF, int NIH>
__device__ __forceinline__ void rdB(const unsigned short* SB, int wn, int fr, int g,
                                    f16x8 (&bf)[2][2]) {
#pragma unroll
    for (int ni2 = 0; ni2 < 2; ni2++)
#pragma unroll
        for (int kk = 0; kk < 2; kk++) {
            int pos = wn * 32 + ni2 * 16 + fr;
            bf[ni2][kk] = *(const f16x8*)(SB + BUF * 16384 + NIH * 8192 + pos * 64 +
                                          (((kk * 4 + g) ^ (fr & 7)) << 3));
        }
}

template<int MIH, int NIH>
__device__ __forceinline__ void mm16(f16x8 (&af)[4][2], f16x8 (&bf)[2][2], f32x4 (&acc)[8][4]) {
    __builtin_amdgcn_s_setprio(1);
#pragma unroll
    for (int m = 0; m < 4; m++)
#pragma unroll
        for (int ni2 = 0; ni2 < 2; ni2++)
#pragma unroll
            for (int kk = 0; kk < 2; kk++)
                acc[MIH * 4 + m][NIH * 2 + ni2] = __builtin_amdgcn_mfma_f32_16x16x32_f16(
                    af[m][kk], bf[ni2][kk], acc[MIH * 4 + m][NIH * 2 + ni2], 0, 0, 0);
    __builtin_amdgcn_s_setprio(0);
}

__global__ __launch_bounds__(512, 1) void k_gemm256(const unsigned short* __restrict__ A,
                                                    const unsigned short* __restrict__ Bt,
                                                    float* __restrict__ C,
                                                    int M, int N, int K, int nbx) {
    __shared__ __align__(16) unsigned short sm[65536];   // 128 KB
    unsigned short* SA = sm;
    unsigned short* SB = sm + 32768;

    int tid = threadIdx.x, lane = tid & 63, wid = tid >> 6;
    int g = lane >> 4, fr = lane & 15;
    int wm = wid >> 2, wn = wid & 3;

    int bid = blockIdx.x;
    int sid = (bid & 7) * ((int)gridDim.x >> 3) + (bid >> 3);
    int by = sid / nbx, bx = sid % nbx;
    int rowA0 = by * 256, colB0 = bx * 256;

    f32x4 acc[8][4];
#pragma unroll
    for (int mi = 0; mi < 8; mi++)
#pragma unroll
        for (int ni = 0; ni < 4; ni++) acc[mi][ni] = (f32x4){0.f, 0.f, 0.f, 0.f};

    auto stA = [&](int buf, int h, int kt) {
#pragma unroll
        for (int t = 0; t < 2; t++) {
            int i = t * 512 + tid;
            int pos = i >> 3;
            int grow = rowA0 + ((pos >> 6) << 7) + h * 64 + (pos & 63);
            int cg = (i & 7) ^ (pos & 7);
            gload16(A + (size_t)grow * K + kt * 64 + cg * 8,
                    SA + buf * 16384 + h * 8192 + pos * 64 + (i & 7) * 8);
        }
    };
    auto stB = [&](int buf, int h, int kt) {
#pragma unroll
        for (int t = 0; t < 2; t++) {
            int i = t * 512 + tid;
            int pos = i >> 3;
            int gcol = colB0 + ((pos >> 5) << 6) + h * 32 + (pos & 31);
            int cg = (i & 7) ^ (pos & 7);
            gload16(Bt + (size_t)gcol * K + kt * 64 + cg * 8,
                    SB + buf * 16384 + h * 8192 + pos * 64 + (i & 7) * 8);
        }
    };

    int nT = K >> 6;
    stA(0, 0, 0); stB(0, 0, 0); stA(0, 1, 0); stB(0, 1, 0);
    stA(1, 0, 1); stB(1, 0, 1);
    VM4();
    GBAR();

    f16x8 af[4][2], bf[2][2];
    int nIt = nT >> 1;
    for (int it = 0; it < nIt; it++) {
        int T = it * 2;
        bool s36 = (T + 2 < nT), s78 = (T + 3 < nT);
        rdA<0, 0>(SA, wm, fr, g, af); rdB<0, 0>(SB, wn, fr, g, bf);
        stA(1, 1, T + 1);
        GBAR(); mm16<0, 0>(af, bf, acc); GBAR();
        rdB<0, 1>(SB, wn, fr, g, bf);
        stB(1, 1, T + 1);
        GBAR(); mm16<0, 1>(af, bf, acc); GBAR();
        rdA<0, 1>(SA, wm, fr, g, af); rdB<0, 0>(SB, wn, fr, g, bf);
        if (s36) stA(0, 0, T + 2);
        GBAR(); mm16<1, 0>(af, bf, acc); GBAR();
        rdB<0, 1>(SB, wn, fr, g, bf);
        if (s36) { stB(0, 0, T + 2); VM4(); } else { VM0(); }
        GBAR(); mm16<1, 1>(af, bf, acc); GBAR();
        rdA<1, 0>(SA, wm, fr, g, af); rdB<1, 0>(SB, wn, fr, g, bf);
        if (s36) stA(0, 1, T + 2);
        GBAR(); mm16<0, 0>(af, bf, acc); GBAR();
        rdB<1, 1>(SB, wn, fr, g, bf);
        if (s36) stB(0, 1, T + 2);
        GBAR(); mm16<0, 1>(af, bf, acc); GBAR();
        rdA<1, 1>(SA, wm, fr, g, af); rdB<1, 0>(SB, wn, fr, g, bf);
        if (s78) stA(1, 0, T + 3);
        GBAR(); mm16<1, 0>(af, bf, acc); GBAR();
        rdB<1, 1>(SB, wn, fr, g, bf);
        if (s78) { stB(1, 0, T + 3); VM4(); } else { VM0(); }
        GBAR(); mm16<1, 1>(af, bf, acc); GBAR();
    }

#pragma unroll
    for (int mi = 0; mi < 8; mi++) {
        int row = rowA0 + wm * 128 + mi * 16 + g * 4;
#pragma unroll
        for (int ni = 0; ni < 4; ni++) {
            int col = colB0 + wn * 64 + ni * 16 + fr;
#pragma unroll
            for (int r = 0; r < 4; r++)
                C[(size_t)(row + r) * N + col] = acc[mi][ni][r];
        }
    }
}

// ---------- RMS/L2 norm + partial RoPE; fp16 outputs ----------
__global__ __launch_bounds__(256) void k_norm_rope(float* __restrict__ qkv,
                                                   const float* __restrict__ q_scale,
                                                   const float* __restrict__ k_scale,
                                                   unsigned short* __restrict__ Qh,
                                                   unsigned short* __restrict__ Kh) {
    __shared__ float Y[256];
    __shared__ float red[4];
    int blk = blockIdx.x;
    int bt = blk >> 4, slot = blk & 15;
    int b = bt >> 11, t = bt & 2047;
    int h = threadIdx.x;
    int lane = h & 63, wid = h >> 6;

    float x = qkv[(size_t)bt * 4096 + slot * 256 + h];
    float v = x * x;
#pragma unroll
    for (int m = 1; m < 64; m <<= 1) v += __shfl_xor(v, m);
    if (lane == 0) red[wid] = v;
    __syncthreads();
    float ss = red[0] + red[1] + red[2] + red[3];

    float y;
    if (slot < 12) {
        float fac = rsqrtf(ss * (1.0f / 256.0f) + 1e-6f);
        const float* sc = (slot < 8) ? q_scale : k_scale;
        y = x * fac * (1.0f + sc[h]);
    } else {
        float fac = rsqrtf(ss + 1e-6f);
        y = x * fac;
    }
    Y[h] = y;
    __syncthreads();

    if (slot < 12) {
        float out;
        int hm = h & 127;
        if (hm < 64) {
            float inv = exp2f(-(float)hm * 0.10381025296522993f); // log2(10000)/128
            float fr = (float)t * inv;
            float s = sinf(fr), c = cosf(fr);
            float y1 = Y[hm], y2 = Y[128 + hm];
            out = (h < 128) ? (y1 * c - y2 * s) : (y2 * c + y1 * s);
        } else {
            out = y;
        }
        unsigned short hv = f2h(out);
        if (slot < 8)
            Qh[((size_t)(b * 8 + slot) * 2048 + t) * 256 + h] = hv;
        else
            Kh[((size_t)(b * 4 + (slot - 8)) * 2048 + t) * 256 + h] = hv;
    } else {
        qkv[(size_t)bt * 4096 + slot * 256 + h] = y;   // normalized v, f32 in-place
    }
}

// ---------- causal flash attention v6: single-buffer, 2 blocks/CU ----------
// grid 512 x 512 thr (8 waves). id = half(1b)|pair(4b)|npar(1b)|bkv(3b): id%8 = bkv
// (XCD-affine); j = half ? 31-pair : pair, so blocks id and id+256 sum to 33 iters
// (round-robin dispatch pairs them per CU). One 64-row q-tile per block, single
// K/V buffer (70.6KB LDS -> 2 blocks/CU); the co-resident block hides stage latency.
// Waves: r2=wid&3 -> 16 q-rows, c2=wid>>2 -> 32-key half; swapped QK^T, in-reg P.
__global__ __launch_bounds__(512, 4) void k_attn(const unsigned short* __restrict__ Qhg,
                                                 const unsigned short* __restrict__ Khg,
                                                 const unsigned short* __restrict__ Vtg,
                                                 unsigned short* __restrict__ attn) {
    __shared__ __align__(16) char smem[70656];
    unsigned short* Ks = (unsigned short*)smem;            // [64*256] fp16, chunk^=(key&7)
    unsigned short* Vs = (unsigned short*)(smem + 32768);  // [256*64] fp16, chunk^=(d&7)
    float* X = (float*)smem;                               // merge overlay [4][64][68] f32
    float* ML = (float*)(smem + 69632);                    // [2][4][16][2] (m,l)

    int id = blockIdx.x;
    int bkv = id & 7;
    int npar = (id >> 3) & 1;
    int pair = (id >> 4) & 15;
    int half = id >> 8;
    int b = bkv >> 2, kv = bkv & 3;
    int n = kv * 2 + npar;
    int bn = b * 8 + n;
    int j = half ? 31 - pair : pair;

    int tid = threadIdx.x, lane = tid & 63, wid = tid >> 6;
    int g = lane >> 4, fr = lane & 15;
    int r2 = wid & 3, c2 = wid >> 2;
    int g4 = g * 4;
    int q0 = j * 64 + r2 * 16;

    const unsigned short* Kh = Khg + (size_t)bkv * 2048 * 256;
    const unsigned short* Vh = Vtg + (size_t)bkv * 256 * 2048;
    const unsigned short* Qb = Qhg + (size_t)bn * 2048 * 256;

    // hoisted staging bases (fixed per thread; advance by kt)
    const unsigned short* kb[4];
    const unsigned short* vb[4];
    int sdst[4];
#pragma unroll
    for (int t2 = 0; t2 < 4; t2++) {
        int c_ = t2 * 512 + tid;
        int r = c_ >> 5, c = (c_ & 31) ^ (r & 7);
        kb[t2] = Kh + (size_t)r * 256 + c * 8;
        int d = c_ >> 3, cv = (c_ & 7) ^ (d & 7);
        vb[t2] = Vh + (size_t)d * 2048 + cv * 8;
        sdst[t2] = c_ * 8;
    }

    // K-read swizzle bases; V-read slots constant per lane
    int krbase[2];
#pragma unroll
    for (int t16 = 0; t16 < 2; t16++) krbase[t16] = (c2 * 32 + t16 * 16 + fr) * 256;
    int s7 = fr & 7;
    int vslot[2];
#pragma unroll
    for (int t16 = 0; t16 < 2; t16++) vslot[t16] = (((c2 * 4 + t16 * 2 + (g >> 1)) ^ s7) << 3) + (g & 1) * 4;

    const unsigned short* qrow = Qb + (size_t)(q0 + fr) * 256;
    f16x8 aq[8];
#pragma unroll
    for (int kk = 0; kk < 8; kk++) aq[kk] = *(const f16x8*)(qrow + kk * 32 + g * 8);

    f32x4 zero4 = {0.f, 0.f, 0.f, 0.f};
    f32x4 o[16];
#pragma unroll
    for (int i2 = 0; i2 < 16; i2++) o[i2] = zero4;
    float m_run = -1e30f;   // per-lane state for q = q0 + fr
    float l_run = 0.f;      // per-lane partial (reduced over g at merge)

    for (int kt = 0; kt <= j; kt++) {
        // stage K (32KB) + V (32KB); __syncthreads drains the gload_lds vmcnt
#pragma unroll
        for (int t2 = 0; t2 < 4; t2++) {
            gload16(kb[t2] + (size_t)kt * 16384, Ks + sdst[t2]);
            gload16(vb[t2] + kt * 64, Vs + sdst[t2]);
        }
        __syncthreads();

        int k0 = kt * 64;

        // S^T = K Q^T over this wave's 32 keys; 4 independent acc chains
        f32x4 se[2] = {zero4, zero4}, so2[2] = {zero4, zero4};
        __builtin_amdgcn_s_setprio(1);
#pragma unroll
        for (int kk = 0; kk < 8; kk += 2) {
#pragma unroll
            for (int t16 = 0; t16 < 2; t16++) {
                f16x8 bk0 = *(const f16x8*)(Ks + krbase[t16] + ((((kk << 2) + g) ^ s7) << 3));
                f16x8 bk1 = *(const f16x8*)(Ks + krbase[t16] + (((((kk + 1) << 2) + g) ^ s7) << 3));
                se[t16] = __builtin_amdgcn_mfma_f32_16x16x32_f16(bk0, aq[kk], se[t16], 0, 0, 0);
                so2[t16] = __builtin_amdgcn_mfma_f32_16x16x32_f16(bk1, aq[kk + 1], so2[t16], 0, 0, 0);
            }
        }
        __builtin_amdgcn_s_setprio(0);

        // softcap 50*tanh(s/50) = 50 - 100/(1+e^{0.04s}), causal mask; all lane-local
        int qg = q0 + fr;
        float pv[2][4];
        float ml = -1e30f;
#pragma unroll
        for (int t16 = 0; t16 < 2; t16++)
#pragma unroll
            for (int r = 0; r < 4; r++) {
                float s = se[t16][r] + so2[t16][r];
                float e = __expf(0.04f * s);
                s = 50.f - 100.f * __builtin_amdgcn_rcpf(1.f + e);
                int key = k0 + c2 * 32 + t16 * 16 + g4 + r;
                if (key > qg) s = -1e9f;
                pv[t16][r] = s;
                ml = fmaxf(ml, s);
            }
        // row-max: in-lane done, reduce over the 4 g-lanes of this q
        ml = fmaxf(ml, __shfl_xor(ml, 16));
        ml = fmaxf(ml, __shfl_xor(ml, 32));

        // defer-max (THR=8)
        if (__any(ml > m_run + 8.f)) {
            float mnew = fmaxf(m_run, ml);
            float swl = __expf(m_run - mnew);
            m_run = mnew;
            l_run *= swl;
            float swr[4];
#pragma unroll
            for (int r = 0; r < 4; r++) swr[r] = __shfl(swl, g4 + r);  // factor for O-row g4+r
#pragma unroll
            for (int nt = 0; nt < 16; nt++)
#pragma unroll
                for (int r = 0; r < 4; r++) o[nt][r] *= swr[r];
        }

        // P = exp(s - m_run), fp16 A-frags for K=16 PV (no data movement)
        f16x4 pf[2];
#pragma unroll
        for (int t16 = 0; t16 < 2; t16++)
#pragma unroll
            for (int r = 0; r < 4; r++) {
                float p = __expf(pv[t16][r] - m_run);
                l_run += p;
                pf[t16][r] = (_Float16)p;
            }

        // O += P V : per nt two K=16 MFMAs (keys t16*16+g4..+3 slice of V)
        __builtin_amdgcn_s_setprio(1);
#pragma unroll
        for (int nt = 0; nt < 16; nt++) {
            int dbase = (nt * 16 + fr) * 64;
            f16x4 bv0 = *(const f16x4*)(Vs + dbase + vslot[0]);
            f16x4 bv1 = *(const f16x4*)(Vs + dbase + vslot[1]);
            o[nt] = MFMA_K16(pf[0], bv0, o[nt]);
            o[nt] = MFMA_K16(pf[1], bv1, o[nt]);
        }
        __builtin_amdgcn_s_setprio(0);
        __syncthreads();   // protect Ks/Vs before next stage / merge overlay
    }

    // merge the two key-half waves (c2=0/1) per rowgroup
    float l2 = l_run + __shfl_xor(l_run, 16);
    l2 += __shfl_xor(l2, 32);
    if (lane < 16) {
        float* mlw = ML + ((c2 * 4 + r2) * 16 + lane) * 2;
        mlw[0] = m_run; mlw[1] = l2;
    }
    __syncthreads();
    float wO[4], li[4];
#pragma unroll
    for (int r = 0; r < 4; r++) {
        int qq = g4 + r;
        const float* p0 = ML + (r2 * 16 + qq) * 2;
        const float* p1 = ML + ((4 + r2) * 16 + qq) * 2;
        float m0 = p0[0], l0 = p0[1], m1 = p1[0], l1 = p1[1];
        float ms = fmaxf(m0, m1);
        float w0 = __expf(m0 - ms), w1 = __expf(m1 - ms);
        li[r] = __builtin_amdgcn_rcpf(fmaxf(l0 * w0 + l1 * w1, 1e-30f));
        wO[r] = c2 ? w1 : w0;
    }
    float* Xl = X + (r2 * 64 + lane) * 68;
    if (c2 == 1) {
#pragma unroll
        for (int nt = 0; nt < 16; nt++)
#pragma unroll
            for (int r = 0; r < 4; r++) Xl[nt * 4 + r] = o[nt][r] * wO[r];
    }
    __syncthreads();
    if (c2 == 0) {
#pragma unroll
        for (int nt = 0; nt < 16; nt++)
#pragma unroll
            for (int r = 0; r < 4; r++) {
                float val = (o[nt][r] * wO[r] + Xl[nt * 4 + r]) * li[r];
                int qr = q0 + g4 + r;
                attn[(size_t)(b * 2048 + qr) * 2048 + n * 256 + nt * 16 + fr] = f2h(val);
            }
    }
}

extern "C" void kernel_launch(void* const* d_in, const int* in_sizes, int n_in,
                              void* d_out, int out_size, void* d_ws, size_t ws_size,
                              hipStream_t stream) {
    const float* x       = (const float*)d_in[0];
    // d_in[1] = attention_mask: deterministically causal -> applied analytically
    const float* Wq      = (const float*)d_in[2];
    const float* Wk      = (const float*)d_in[3];
    const float* Wv      = (const float*)d_in[4];
    const float* Wo      = (const float*)d_in[5];
    const float* q_scale = (const float*)d_in[6];
    const float* k_scale = (const float*)d_in[7];
    float* out = (float*)d_out;
    char* ws = (char*)d_ws;

    // workspace (peak 104 MB):
    //   [0,16M):   xh fp16 -> dead after GEMM1 -> Qh fp16 [16][2048][256]
    //   [16M,32M): WT fp16 (qkv weights B^T) -> dead after GEMM1 -> Kh[16,24M) Vt[24,32M)
    //   [32M,40M): WoT fp16
    //   [40M,104M): qkv f32 4096x4096 -> dead after V-transpose -> attnb fp16 [40,56M)
    const size_t MB = 1024 * 1024;
    unsigned short* xh    = (unsigned short*)ws;
    unsigned short* Qh    = (unsigned short*)ws;
    unsigned short* WT    = (unsigned short*)(ws + 16 * MB);
    unsigned short* Kh    = (unsigned short*)(ws + 16 * MB);
    unsigned short* Vt    = (unsigned short*)(ws + 24 * MB);
    unsigned short* WoT   = (unsigned short*)(ws + 32 * MB);
    float*          qkv   = (float*)(ws + 40 * MB);
    unsigned short* attnb = (unsigned short*)(ws + 40 * MB);

    dim3 tb(32, 8);
    k_cvt<<<dim3(8192), dim3(256), 0, stream>>>(x, xh, 2097152);
    k_transpose_cvt<<<dim3(8, 64, 8), tb, 0, stream>>>(Wq, WT, 256, 2048, 524288L, 524288L);
    k_transpose_cvt<<<dim3(8, 64, 4), tb, 0, stream>>>(Wk, WT + (size_t)2048 * 2048, 256, 2048, 524288L, 524288L);
    k_transpose_cvt<<<dim3(8, 64, 4), tb, 0, stream>>>(Wv, WT + (size_t)3072 * 2048, 256, 2048, 524288L, 524288L);

    k_gemm256<<<dim3(256), dim3(512), 0, stream>>>(xh, WT, qkv, 4096, 4096, 2048, 16);
    k_norm_rope<<<dim3(65536), dim3(256), 0, stream>>>(qkv, q_scale, k_scale, Qh, Kh);
    for (int b = 0; b < 2; b++)
        k_transpose_cvt<<<dim3(8, 64, 4), tb, 0, stream>>>(qkv + (size_t)b * 2048 * 4096 + 3072,
                                                           Vt + (size_t)b * 4 * 256 * 2048,
                                                           4096, 2048, 256L, 524288L);
    k_attn<<<dim3(512), dim3(512), 0, stream>>>(Qh, Kh, Vt, attnb);

    k_transpose_cvt<<<dim3(64, 64, 1), tb, 0, stream>>>(Wo, WoT, 2048, 2048, 0L, 0L);
    k_gemm256<<<dim3(128), dim3(512), 0, stream>>>(attnb, WoT, out, 4096, 2048, 2048, 8);
}

// Round 10
// 285.095 us; speedup vs baseline: 1.2639x; 1.2639x over previous
//
#include <hip/hip_runtime.h>

#define AS1 __attribute__((address_space(1)))
#define AS3 __attribute__((address_space(3)))

typedef __attribute__((ext_vector_type(8))) _Float16 f16x8;
typedef __attribute__((ext_vector_type(4))) _Float16 f16x4;
typedef __attribute__((ext_vector_type(4))) float f32x4;

#define MFMA_K16(a, b, c) __builtin_amdgcn_mfma_f32_16x16x16f16(a, b, c, 0, 0, 0)

__device__ __forceinline__ unsigned short f2h(float f) {
    union { _Float16 h; unsigned short u; } v; v.h = (_Float16)f; return v.u;
}

__device__ __forceinline__ void gload16(const void* g, void* l) {
    __builtin_amdgcn_global_load_lds((const AS1 unsigned int*)g, (AS3 unsigned int*)l, 16, 0, 0);
}

#define GBAR() __builtin_amdgcn_s_barrier()
#define VM4()  asm volatile("s_waitcnt vmcnt(4)" ::: "memory")
#define VM0()  asm volatile("s_waitcnt vmcnt(0)" ::: "memory")

// ---------- f32 -> fp16 elementwise (x4 vectorized) ----------
__global__ __launch_bounds__(256) void k_cvt(const float* __restrict__ src,
                                             unsigned short* __restrict__ dst, int n4) {
    int i = blockIdx.x * 256 + threadIdx.x;
    if (i >= n4) return;
    float4 v = ((const float4*)src)[i];
    ushort4 o;
    o.x = f2h(v.x); o.y = f2h(v.y); o.z = f2h(v.z); o.w = f2h(v.w);
    ((ushort4*)dst)[i] = o;
}

// ---------- tiled transpose + convert: dst[c*ld_dst + r] = fp16(src[r*ld_src + c]) ----------
__global__ __launch_bounds__(256) void k_transpose_cvt(const float* __restrict__ src,
                                                       unsigned short* __restrict__ dst,
                                                       int ld_src, int ld_dst,
                                                       long zs_src, long zs_dst) {
    __shared__ float tile[32][33];
    long sb = (long)blockIdx.z * zs_src;
    long db = (long)blockIdx.z * zs_dst;
    int c0 = blockIdx.x * 32, r0 = blockIdx.y * 32;
    int tx = threadIdx.x, ty = threadIdx.y;
#pragma unroll
    for (int i = 0; i < 4; i++)
        tile[ty + i * 8][tx] = src[sb + (long)(r0 + ty + i * 8) * ld_src + c0 + tx];
    __syncthreads();
#pragma unroll
    for (int i = 0; i < 4; i++)
        dst[db + (long)(c0 + ty + i * 8) * ld_dst + r0 + tx] = f2h(tile[tx][ty + i * 8]);
}

// ======== 256x256 8-phase fp16 GEMM (T2+T3+T4+T5): C = A(MxK) * Bt(NxK)^T, f32 out ========
template<int BUF, int MIH>
__device__ __forceinline__ void rdA(const unsigned short* SA, int wm, int fr, int g,
                                    f16x8 (&af)[4][2]) {
#pragma unroll
    for (int m = 0; m < 4; m++)
#pragma unroll
        for (int kk = 0; kk < 2; kk++) {
            int pos = wm * 64 + m * 16 + fr;
            af[m][kk] = *(const f16x8*)(SA + BUF * 16384 + MIH * 8192 + pos * 64 +
                                        (((kk * 4 + g) ^ (fr & 7)) << 3));
        }
}

template<int BUF, int NIH>
__device__ __forceinline__ void rdB(const unsigned short* SB, int wn, int fr, int g,
                                    f16x8 (&bf)[2][2]) {
#pragma unroll
    for (int ni2 = 0; ni2 < 2; ni2++)
#pragma unroll
        for (int kk = 0; kk < 2; kk++) {
            int pos = wn * 32 + ni2 * 16 + fr;
            bf[ni2][kk] = *(const f16x8*)(SB + BUF * 16384 + NIH * 8192 + pos * 64 +
                                          (((kk * 4 + g) ^ (fr & 7)) << 3));
        }
}

template<int MIH, int NIH>
__device__ __forceinline__ void mm16(f16x8 (&af)[4][2], f16x8 (&bf)[2][2], f32x4 (&acc)[8][4]) {
    __builtin_amdgcn_s_setprio(1);
#pragma unroll
    for (int m = 0; m < 4; m++)
#pragma unroll
        for (int ni2 = 0; ni2 < 2; ni2++)
#pragma unroll
            for (int kk = 0; kk < 2; kk++)
                acc[MIH * 4 + m][NIH * 2 + ni2] = __builtin_amdgcn_mfma_f32_16x16x32_f16(
                    af[m][kk], bf[ni2][kk], acc[MIH * 4 + m][NIH * 2 + ni2], 0, 0, 0);
    __builtin_amdgcn_s_setprio(0);
}

__global__ __launch_bounds__(512, 1) void k_gemm256(const unsigned short* __restrict__ A,
                                                    const unsigned short* __restrict__ Bt,
                                                    float* __restrict__ C,
                                                    int M, int N, int K, int nbx) {
    __shared__ __align__(16) unsigned short sm[65536];   // 128 KB
    unsigned short* SA = sm;
    unsigned short* SB = sm + 32768;

    int tid = threadIdx.x, lane = tid & 63, wid = tid >> 6;
    int g = lane >> 4, fr = lane & 15;
    int wm = wid >> 2, wn = wid & 3;

    int bid = blockIdx.x;
    int sid = (bid & 7) * ((int)gridDim.x >> 3) + (bid >> 3);
    int by = sid / nbx, bx = sid % nbx;
    int rowA0 = by * 256, colB0 = bx * 256;

    f32x4 acc[8][4];
#pragma unroll
    for (int mi = 0; mi < 8; mi++)
#pragma unroll
        for (int ni = 0; ni < 4; ni++) acc[mi][ni] = (f32x4){0.f, 0.f, 0.f, 0.f};

    auto stA = [&](int buf, int h, int kt) {
#pragma unroll
        for (int t = 0; t < 2; t++) {
            int i = t * 512 + tid;
            int pos = i >> 3;
            int grow = rowA0 + ((pos >> 6) << 7) + h * 64 + (pos & 63);
            int cg = (i & 7) ^ (pos & 7);
            gload16(A + (size_t)grow * K + kt * 64 + cg * 8,
                    SA + buf * 16384 + h * 8192 + pos * 64 + (i & 7) * 8);
        }
    };
    auto stB = [&](int buf, int h, int kt) {
#pragma unroll
        for (int t = 0; t < 2; t++) {
            int i = t * 512 + tid;
            int pos = i >> 3;
            int gcol = colB0 + ((pos >> 5) << 6) + h * 32 + (pos & 31);
            int cg = (i & 7) ^ (pos & 7);
            gload16(Bt + (size_t)gcol * K + kt * 64 + cg * 8,
                    SB + buf * 16384 + h * 8192 + pos * 64 + (i & 7) * 8);
        }
    };

    int nT = K >> 6;
    stA(0, 0, 0); stB(0, 0, 0); stA(0, 1, 0); stB(0, 1, 0);
    stA(1, 0, 1); stB(1, 0, 1);
    VM4();
    GBAR();

    f16x8 af[4][2], bf[2][2];
    int nIt = nT >> 1;
    for (int it = 0; it < nIt; it++) {
        int T = it * 2;
        bool s36 = (T + 2 < nT), s78 = (T + 3 < nT);
        rdA<0, 0>(SA, wm, fr, g, af); rdB<0, 0>(SB, wn, fr, g, bf);
        stA(1, 1, T + 1);
        GBAR(); mm16<0, 0>(af, bf, acc); GBAR();
        rdB<0, 1>(SB, wn, fr, g, bf);
        stB(1, 1, T + 1);
        GBAR(); mm16<0, 1>(af, bf, acc); GBAR();
        rdA<0, 1>(SA, wm, fr, g, af); rdB<0, 0>(SB, wn, fr, g, bf);
        if (s36) stA(0, 0, T + 2);
        GBAR(); mm16<1, 0>(af, bf, acc); GBAR();
        rdB<0, 1>(SB, wn, fr, g, bf);
        if (s36) { stB(0, 0, T + 2); VM4(); } else { VM0(); }
        GBAR(); mm16<1, 1>(af, bf, acc); GBAR();
        rdA<1, 0>(SA, wm, fr, g, af); rdB<1, 0>(SB, wn, fr, g, bf);
        if (s36) stA(0, 1, T + 2);
        GBAR(); mm16<0, 0>(af, bf, acc); GBAR();
        rdB<1, 1>(SB, wn, fr, g, bf);
        if (s36) stB(0, 1, T + 2);
        GBAR(); mm16<0, 1>(af, bf, acc); GBAR();
        rdA<1, 1>(SA, wm, fr, g, af); rdB<1, 0>(SB, wn, fr, g, bf);
        if (s78) stA(1, 0, T + 3);
        GBAR(); mm16<1, 0>(af, bf, acc); GBAR();
        rdB<1, 1>(SB, wn, fr, g, bf);
        if (s78) { stB(1, 0, T + 3); VM4(); } else { VM0(); }
        GBAR(); mm16<1, 1>(af, bf, acc); GBAR();
    }

#pragma unroll
    for (int mi = 0; mi < 8; mi++) {
        int row = rowA0 + wm * 128 + mi * 16 + g * 4;
#pragma unroll
        for (int ni = 0; ni < 4; ni++) {
            int col = colB0 + wn * 64 + ni * 16 + fr;
#pragma unroll
            for (int r = 0; r < 4; r++)
                C[(size_t)(row + r) * N + col] = acc[mi][ni][r];
        }
    }
}

// ---------- fp16 GEMM (out-proj): C = A(MxK) * Bt(NxK)^T, f32 out. 128x128 tile ----------
__global__ __launch_bounds__(256) void k_gemm_f16(const unsigned short* __restrict__ A,
                                                  const unsigned short* __restrict__ Bt,
                                                  float* __restrict__ C,
                                                  int M, int N, int K) {
    __shared__ unsigned short As[128 * 64];
    __shared__ unsigned short Bs[128 * 64];
    int tid = threadIdx.x;
    int lane = tid & 63, wid = tid >> 6;
    int g = lane >> 4, fr = lane & 15;
    int rowA0 = blockIdx.y * 128;
    int colB0 = blockIdx.x * 128;

    f32x4 zero = {0.f, 0.f, 0.f, 0.f};
    f32x4 acc[4][4];
#pragma unroll
    for (int mi = 0; mi < 4; mi++)
#pragma unroll
        for (int ni = 0; ni < 4; ni++) acc[mi][ni] = zero;

    const unsigned short* ag[4];
    const unsigned short* bg[4];
#pragma unroll
    for (int j = 0; j < 4; j++) {
        int id = j * 256 + tid;
        int r = id >> 3;
        int c = (id & 7) ^ (r & 7);
        ag[j] = A + (size_t)(rowA0 + r) * K + c * 8;
        bg[j] = Bt + (size_t)(colB0 + r) * K + c * 8;
    }

    int nK = K >> 6;
    for (int kt = 0; kt < nK; kt++) {
#pragma unroll
        for (int j = 0; j < 4; j++) {
            int id = j * 256 + tid;
            gload16(ag[j], As + id * 8);
            gload16(bg[j], Bs + id * 8);
            ag[j] += 64; bg[j] += 64;
        }
        __syncthreads();
#pragma unroll
        for (int kk = 0; kk < 2; kk++) {
            f16x8 af[4], bfr[4];
#pragma unroll
            for (int mi = 0; mi < 4; mi++) {
                int r = (wid >> 1) * 64 + mi * 16 + fr;
                af[mi] = *(const f16x8*)(As + r * 64 + ((((kk << 2) + g) ^ (r & 7)) << 3));
            }
#pragma unroll
            for (int ni = 0; ni < 4; ni++) {
                int r = (wid & 1) * 64 + ni * 16 + fr;
                bfr[ni] = *(const f16x8*)(Bs + r * 64 + ((((kk << 2) + g) ^ (r & 7)) << 3));
            }
#pragma unroll
            for (int mi = 0; mi < 4; mi++)
#pragma unroll
                for (int ni = 0; ni < 4; ni++)
                    acc[mi][ni] = __builtin_amdgcn_mfma_f32_16x16x32_f16(af[mi], bfr[ni], acc[mi][ni], 0, 0, 0);
        }
        __syncthreads();
    }

#pragma unroll
    for (int mi = 0; mi < 4; mi++) {
        int row = rowA0 + (wid >> 1) * 64 + mi * 16 + g * 4;
#pragma unroll
        for (int ni = 0; ni < 4; ni++) {
            int col = colB0 + (wid & 1) * 64 + ni * 16 + fr;
#pragma unroll
            for (int r = 0; r < 4; r++)
                C[(size_t)(row + r) * N + col] = acc[mi][ni][r];
        }
    }
}

// ---------- RMS/L2 norm + partial RoPE; fp16 outputs ----------
__global__ __launch_bounds__(256) void k_norm_rope(float* __restrict__ qkv,
                                                   const float* __restrict__ q_scale,
                                                   const float* __restrict__ k_scale,
                                                   unsigned short* __restrict__ Qh,
                                                   unsigned short* __restrict__ Kh) {
    __shared__ float Y[256];
    __shared__ float red[4];
    int blk = blockIdx.x;
    int bt = blk >> 4, slot = blk & 15;
    int b = bt >> 11, t = bt & 2047;
    int h = threadIdx.x;
    int lane = h & 63, wid = h >> 6;

    float x = qkv[(size_t)bt * 4096 + slot * 256 + h];
    float v = x * x;
#pragma unroll
    for (int m = 1; m < 64; m <<= 1) v += __shfl_xor(v, m);
    if (lane == 0) red[wid] = v;
    __syncthreads();
    float ss = red[0] + red[1] + red[2] + red[3];

    float y;
    if (slot < 12) {
        float fac = rsqrtf(ss * (1.0f / 256.0f) + 1e-6f);
        const float* sc = (slot < 8) ? q_scale : k_scale;
        y = x * fac * (1.0f + sc[h]);
    } else {
        float fac = rsqrtf(ss + 1e-6f);
        y = x * fac;
    }
    Y[h] = y;
    __syncthreads();

    if (slot < 12) {
        float out;
        int hm = h & 127;
        if (hm < 64) {
            float inv = exp2f(-(float)hm * 0.10381025296522993f); // log2(10000)/128
            float fr = (float)t * inv;
            float s = sinf(fr), c = cosf(fr);
            float y1 = Y[hm], y2 = Y[128 + hm];
            out = (h < 128) ? (y1 * c - y2 * s) : (y2 * c + y1 * s);
        } else {
            out = y;
        }
        unsigned short hv = f2h(out);
        if (slot < 8)
            Qh[((size_t)(b * 8 + slot) * 2048 + t) * 256 + h] = hv;
        else
            Kh[((size_t)(b * 4 + (slot - 8)) * 2048 + t) * 256 + h] = hv;
    } else {
        qkv[(size_t)bt * 4096 + slot * 256 + h] = y;   // normalized v, f32 in-place
    }
}

// ---------- causal flash attention v6b: single-buffer, 2 blocks/CU, no reg cap ----------
// grid 512 x 512 thr (8 waves). id = half(1b)|pair(4b)|npar(1b)|bkv(3b): id%8 = bkv
// (XCD-affine); j = half ? 31-pair : pair. One 64-row q-tile per block, single K/V
// buffer (70.6KB LDS -> 2 blocks/CU; ~108 VGPR <= 128 so VGPRs allow 4 waves/SIMD).
// NOTE: launch_bounds min-waves=2 (NOT 4): 4 forced a 128-reg budget -> o[16] spilled
// to scratch (r9: VGPR 64, WRITE_SIZE 60MB, 163µs). Co-resident block hides staging.
__global__ __launch_bounds__(512, 2) void k_attn(const unsigned short* __restrict__ Qhg,
                                                 const unsigned short* __restrict__ Khg,
                                                 const unsigned short* __restrict__ Vtg,
                                                 unsigned short* __restrict__ attn) {
    __shared__ __align__(16) char smem[70656];
    unsigned short* Ks = (unsigned short*)smem;            // [64*256] fp16, chunk^=(key&7)
    unsigned short* Vs = (unsigned short*)(smem + 32768);  // [256*64] fp16, chunk^=(d&7)
    float* X = (float*)smem;                               // merge overlay [4][64][68] f32
    float* ML = (float*)(smem + 69632);                    // [2][4][16][2] (m,l)

    int id = blockIdx.x;
    int bkv = id & 7;
    int npar = (id >> 3) & 1;
    int pair = (id >> 4) & 15;
    int half = id >> 8;
    int b = bkv >> 2, kv = bkv & 3;
    int n = kv * 2 + npar;
    int bn = b * 8 + n;
    int j = half ? 31 - pair : pair;

    int tid = threadIdx.x, lane = tid & 63, wid = tid >> 6;
    int g = lane >> 4, fr = lane & 15;
    int r2 = wid & 3, c2 = wid >> 2;
    int g4 = g * 4;
    int q0 = j * 64 + r2 * 16;

    const unsigned short* Kh = Khg + (size_t)bkv * 2048 * 256;
    const unsigned short* Vh = Vtg + (size_t)bkv * 256 * 2048;
    const unsigned short* Qb = Qhg + (size_t)bn * 2048 * 256;

    // hoisted staging bases (fixed per thread; advance by kt)
    const unsigned short* kb[4];
    const unsigned short* vb[4];
    int sdst[4];
#pragma unroll
    for (int t2 = 0; t2 < 4; t2++) {
        int c_ = t2 * 512 + tid;
        int r = c_ >> 5, c = (c_ & 31) ^ (r & 7);
        kb[t2] = Kh + (size_t)r * 256 + c * 8;
        int d = c_ >> 3, cv = (c_ & 7) ^ (d & 7);
        vb[t2] = Vh + (size_t)d * 2048 + cv * 8;
        sdst[t2] = c_ * 8;
    }

    // K-read swizzle bases; V-read slots constant per lane
    int krbase[2];
#pragma unroll
    for (int t16 = 0; t16 < 2; t16++) krbase[t16] = (c2 * 32 + t16 * 16 + fr) * 256;
    int s7 = fr & 7;
    int vslot[2];
#pragma unroll
    for (int t16 = 0; t16 < 2; t16++) vslot[t16] = (((c2 * 4 + t16 * 2 + (g >> 1)) ^ s7) << 3) + (g & 1) * 4;

    const unsigned short* qrow = Qb + (size_t)(q0 + fr) * 256;
    f16x8 aq[8];
#pragma unroll
    for (int kk = 0; kk < 8; kk++) aq[kk] = *(const f16x8*)(qrow + kk * 32 + g * 8);

    f32x4 zero4 = {0.f, 0.f, 0.f, 0.f};
    f32x4 o[16];
#pragma unroll
    for (int i2 = 0; i2 < 16; i2++) o[i2] = zero4;
    float m_run = -1e30f;   // per-lane state for q = q0 + fr
    float l_run = 0.f;      // per-lane partial (reduced over g at merge)

    for (int kt = 0; kt <= j; kt++) {
        // stage K (32KB) + V (32KB); __syncthreads drains the gload_lds vmcnt
#pragma unroll
        for (int t2 = 0; t2 < 4; t2++) {
            gload16(kb[t2] + (size_t)kt * 16384, Ks + sdst[t2]);
            gload16(vb[t2] + kt * 64, Vs + sdst[t2]);
        }
        __syncthreads();

        int k0 = kt * 64;

        // S^T = K Q^T over this wave's 32 keys; 4 independent acc chains
        f32x4 se[2] = {zero4, zero4}, so2[2] = {zero4, zero4};
        __builtin_amdgcn_s_setprio(1);
#pragma unroll
        for (int kk = 0; kk < 8; kk += 2) {
#pragma unroll
            for (int t16 = 0; t16 < 2; t16++) {
                f16x8 bk0 = *(const f16x8*)(Ks + krbase[t16] + ((((kk << 2) + g) ^ s7) << 3));
                f16x8 bk1 = *(const f16x8*)(Ks + krbase[t16] + (((((kk + 1) << 2) + g) ^ s7) << 3));
                se[t16] = __builtin_amdgcn_mfma_f32_16x16x32_f16(bk0, aq[kk], se[t16], 0, 0, 0);
                so2[t16] = __builtin_amdgcn_mfma_f32_16x16x32_f16(bk1, aq[kk + 1], so2[t16], 0, 0, 0);
            }
        }
        __builtin_amdgcn_s_setprio(0);

        // softcap 50*tanh(s/50) = 50 - 100/(1+e^{0.04s}), causal mask; all lane-local
        int qg = q0 + fr;
        float pv[2][4];
        float ml = -1e30f;
#pragma unroll
        for (int t16 = 0; t16 < 2; t16++)
#pragma unroll
            for (int r = 0; r < 4; r++) {
                float s = se[t16][r] + so2[t16][r];
                float e = __expf(0.04f * s);
                s = 50.f - 100.f * __builtin_amdgcn_rcpf(1.f + e);
                int key = k0 + c2 * 32 + t16 * 16 + g4 + r;
                if (key > qg) s = -1e9f;
                pv[t16][r] = s;
                ml = fmaxf(ml, s);
            }
        // row-max: in-lane done, reduce over the 4 g-lanes of this q
        ml = fmaxf(ml, __shfl_xor(ml, 16));
        ml = fmaxf(ml, __shfl_xor(ml, 32));

        // defer-max (THR=8)
        if (__any(ml > m_run + 8.f)) {
            float mnew = fmaxf(m_run, ml);
            float swl = __expf(m_run - mnew);
            m_run = mnew;
            l_run *= swl;
            float swr[4];
#pragma unroll
            for (int r = 0; r < 4; r++) swr[r] = __shfl(swl, g4 + r);  // factor for O-row g4+r
#pragma unroll
            for (int nt = 0; nt < 16; nt++)
#pragma unroll
                for (int r = 0; r < 4; r++) o[nt][r] *= swr[r];
        }

        // P = exp(s - m_run), fp16 A-frags for K=16 PV (no data movement)
        f16x4 pf[2];
#pragma unroll
        for (int t16 = 0; t16 < 2; t16++)
#pragma unroll
            for (int r = 0; r < 4; r++) {
                float p = __expf(pv[t16][r] - m_run);
                l_run += p;
                pf[t16][r] = (_Float16)p;
            }

        // O += P V : per nt two K=16 MFMAs (keys t16*16+g4..+3 slice of V)
        __builtin_amdgcn_s_setprio(1);
#pragma unroll
        for (int nt = 0; nt < 16; nt++) {
            int dbase = (nt * 16 + fr) * 64;
            f16x4 bv0 = *(const f16x4*)(Vs + dbase + vslot[0]);
            f16x4 bv1 = *(const f16x4*)(Vs + dbase + vslot[1]);
            o[nt] = MFMA_K16(pf[0], bv0, o[nt]);
            o[nt] = MFMA_K16(pf[1], bv1, o[nt]);
        }
        __builtin_amdgcn_s_setprio(0);
        __syncthreads();   // protect Ks/Vs before next stage / merge overlay
    }

    // merge the two key-half waves (c2=0/1) per rowgroup
    float l2 = l_run + __shfl_xor(l_run, 16);
    l2 += __shfl_xor(l2, 32);
    if (lane < 16) {
        float* mlw = ML + ((c2 * 4 + r2) * 16 + lane) * 2;
        mlw[0] = m_run; mlw[1] = l2;
    }
    __syncthreads();
    float wO[4], li[4];
#pragma unroll
    for (int r = 0; r < 4; r++) {
        int qq = g4 + r;
        const float* p0 = ML + (r2 * 16 + qq) * 2;
        const float* p1 = ML + ((4 + r2) * 16 + qq) * 2;
        float m0 = p0[0], l0 = p0[1], m1 = p1[0], l1 = p1[1];
        float ms = fmaxf(m0, m1);
        float w0 = __expf(m0 - ms), w1 = __expf(m1 - ms);
        li[r] = __builtin_amdgcn_rcpf(fmaxf(l0 * w0 + l1 * w1, 1e-30f));
        wO[r] = c2 ? w1 : w0;
    }
    float* Xl = X + (r2 * 64 + lane) * 68;
    if (c2 == 1) {
#pragma unroll
        for (int nt = 0; nt < 16; nt++)
#pragma unroll
            for (int r = 0; r < 4; r++) Xl[nt * 4 + r] = o[nt][r] * wO[r];
    }
    __syncthreads();
    if (c2 == 0) {
#pragma unroll
        for (int nt = 0; nt < 16; nt++)
#pragma unroll
            for (int r = 0; r < 4; r++) {
                float val = (o[nt][r] * wO[r] + Xl[nt * 4 + r]) * li[r];
                int qr = q0 + g4 + r;
                attn[(size_t)(b * 2048 + qr) * 2048 + n * 256 + nt * 16 + fr] = f2h(val);
            }
    }
}

extern "C" void kernel_launch(void* const* d_in, const int* in_sizes, int n_in,
                              void* d_out, int out_size, void* d_ws, size_t ws_size,
                              hipStream_t stream) {
    const float* x       = (const float*)d_in[0];
    // d_in[1] = attention_mask: deterministically causal -> applied analytically
    const float* Wq      = (const float*)d_in[2];
    const float* Wk      = (const float*)d_in[3];
    const float* Wv      = (const float*)d_in[4];
    const float* Wo      = (const float*)d_in[5];
    const float* q_scale = (const float*)d_in[6];
    const float* k_scale = (const float*)d_in[7];
    float* out = (float*)d_out;
    char* ws = (char*)d_ws;

    // workspace (peak 104 MB):
    //   [0,16M):   xh fp16 -> dead after GEMM1 -> Qh fp16 [16][2048][256]
    //   [16M,32M): WT fp16 (qkv weights B^T) -> dead after GEMM1 -> Kh[16,24M) Vt[24,32M)
    //   [32M,40M): WoT fp16
    //   [40M,104M): qkv f32 4096x4096 -> dead after V-transpose -> attnb fp16 [40,56M)
    const size_t MB = 1024 * 1024;
    unsigned short* xh    = (unsigned short*)ws;
    unsigned short* Qh    = (unsigned short*)ws;
    unsigned short* WT    = (unsigned short*)(ws + 16 * MB);
    unsigned short* Kh    = (unsigned short*)(ws + 16 * MB);
    unsigned short* Vt    = (unsigned short*)(ws + 24 * MB);
    unsigned short* WoT   = (unsigned short*)(ws + 32 * MB);
    float*          qkv   = (float*)(ws + 40 * MB);
    unsigned short* attnb = (unsigned short*)(ws + 40 * MB);

    dim3 tb(32, 8);
    k_cvt<<<dim3(8192), dim3(256), 0, stream>>>(x, xh, 2097152);
    k_transpose_cvt<<<dim3(8, 64, 8), tb, 0, stream>>>(Wq, WT, 256, 2048, 524288L, 524288L);
    k_transpose_cvt<<<dim3(8, 64, 4), tb, 0, stream>>>(Wk, WT + (size_t)2048 * 2048, 256, 2048, 524288L, 524288L);
    k_transpose_cvt<<<dim3(8, 64, 4), tb, 0, stream>>>(Wv, WT + (size_t)3072 * 2048, 256, 2048, 524288L, 524288L);

    k_gemm256<<<dim3(256), dim3(512), 0, stream>>>(xh, WT, qkv, 4096, 4096, 2048, 16);
    k_norm_rope<<<dim3(65536), dim3(256), 0, stream>>>(qkv, q_scale, k_scale, Qh, Kh);
    for (int b = 0; b < 2; b++)
        k_transpose_cvt<<<dim3(8, 64, 4), tb, 0, stream>>>(qkv + (size_t)b * 2048 * 4096 + 3072,
                                                           Vt + (size_t)b * 4 * 256 * 2048,
                                                           4096, 2048, 256L, 524288L);
    k_attn<<<dim3(512), dim3(512), 0, stream>>>(Qh, Kh, Vt, attnb);

    k_transpose_cvt<<<dim3(64, 64, 1), tb, 0, stream>>>(Wo, WoT, 2048, 2048, 0L, 0L);
    k_gemm_f16<<<dim3(16, 32), dim3(256), 0, stream>>>(attnb, WoT, out, 4096, 2048, 2048);
}